// Round 9
// baseline (4218.860 us; speedup 1.0000x reference)
//
#include <hip/hip_runtime.h>

typedef unsigned int uint;
typedef unsigned long long u64;
typedef unsigned short ushort;
typedef _Float16 f16;
typedef _Float16 f16x2 __attribute__((ext_vector_type(2)));
typedef _Float16 f16x8 __attribute__((ext_vector_type(8)));
typedef float f32x4 __attribute__((ext_vector_type(4)));

#define N_TYPES 10000
#define HID 256
#define G4 1024
#define BATCH 32
#define SEQ 1024

// ---------------- K1: path table: path[n][h] = sum_d cumw_d * emb[anc[n,d]][h]
__global__ void k_path(const int* __restrict__ anc, const float* __restrict__ weight,
                       const float* __restrict__ emb, int D, f16* __restrict__ path) {
  int n = blockIdx.x;
  int h = threadIdx.x;
  float acc = 0.f, cw = 1.f;
  for (int d = 0; d < D; ++d) {
    int a = anc[n * D + d];
    if (a < 0) break;
    acc += cw * emb[a * HID + h];
    cw *= weight[a];
  }
  path[n * HID + h] = (f16)acc;
}

// ---------------- K0: convert W_ih -> f16, W_hh -> transposed packed f16 pairs, bias = b_ih+b_hh
// whh_t layout: [128 kpair][1024 row] u32 (pair = f16 k, k+1 of row)
__global__ void k_conv(const float* __restrict__ wih, const float* __restrict__ whh,
                       const float* __restrict__ bih, const float* __restrict__ bhh,
                       f16* __restrict__ wih_h, uint* __restrict__ whh_t,
                       float* __restrict__ bias) {
  int i = blockIdx.x * 256 + threadIdx.x;   // 262144 threads
  wih_h[i] = (f16)wih[i];
  if (i < G4 * 128) {
    int row = i >> 7, p = i & 127;
    f16x2 v;
    v.x = (f16)whh[row * HID + 2 * p];
    v.y = (f16)whh[row * HID + 2 * p + 1];
    whh_t[p * G4 + row] = __builtin_bit_cast(uint, v);
  }
  if (i < G4) bias[i] = bih[i] + bhh[i];
}

// ---------------- K2: proj[n][dim][gate] = path[n]@W_ih^T + b (gate-packed epilogue)
#define BM 128
#define BN 128
#define BK 64
#define LPAD 72
__global__ __launch_bounds__(256) void k_gemm(const f16* __restrict__ A,
                                              const f16* __restrict__ Bw,
                                              const float* __restrict__ bias,
                                              f16* __restrict__ C) {
  __shared__ f16 sA[BM][LPAD];
  __shared__ f16 sB[BN][LPAD];
  int m0 = blockIdx.x * BM, n0 = blockIdx.y * BN;
  int tid = threadIdx.x;
  int wid = tid >> 6, lane = tid & 63;
  int wm = wid & 1, wn = wid >> 1;
  f32x4 acc[4][4] = {};
  for (int k0 = 0; k0 < 256; k0 += BK) {
    __syncthreads();
    int r = tid >> 3, kc = (tid & 7) * 8;
    for (int i = 0; i < 4; ++i) {
      int row = r + 32 * i;
      int gm = m0 + row;
      uint4 va = make_uint4(0u, 0u, 0u, 0u);
      if (gm < N_TYPES) va = *(const uint4*)&A[gm * 256 + k0 + kc];
      *(uint4*)&sA[row][kc] = va;
      uint4 vb = *(const uint4*)&Bw[(n0 + row) * 256 + k0 + kc];
      *(uint4*)&sB[row][kc] = vb;
    }
    __syncthreads();
#pragma unroll
    for (int ks = 0; ks < 2; ++ks) {
      f16x8 af[4], bf[4];
      int kk = ks * 32 + (lane >> 4) * 8;
#pragma unroll
      for (int mt = 0; mt < 4; ++mt)
        af[mt] = *(const f16x8*)&sA[wm * 64 + mt * 16 + (lane & 15)][kk];
#pragma unroll
      for (int nt = 0; nt < 4; ++nt)
        bf[nt] = *(const f16x8*)&sB[wn * 64 + nt * 16 + (lane & 15)][kk];
#pragma unroll
      for (int mt = 0; mt < 4; ++mt)
#pragma unroll
        for (int nt = 0; nt < 4; ++nt)
          acc[mt][nt] = __builtin_amdgcn_mfma_f32_16x16x32_f16(af[mt], bf[nt], acc[mt][nt], 0, 0, 0);
    }
  }
#pragma unroll
  for (int mt = 0; mt < 4; ++mt)
#pragma unroll
    for (int nt = 0; nt < 4; ++nt)
#pragma unroll
      for (int qq = 0; qq < 4; ++qq) {
        int row = m0 + wm * 64 + mt * 16 + (lane >> 4) * 4 + qq;
        int col = n0 + wn * 64 + nt * 16 + (lane & 15);
        int dim = col & 255, g = col >> 8;
        if (row < N_TYPES)
          C[row * G4 + dim * 4 + g] = (f16)(acc[mt][nt][qq] + bias[col]);
      }
}

// ---------------- K3: LSTM recurrence, v8: XCD-L2 handoff with GUARANTEED-L1-proof ops.
// Skeleton proven R5-R7: 256 WGs of 512 thr, bid=q*32+b; WG q owns dims [q*32,+32) x
// 4 gates = 128 rows, k-split over 4 waves (kq=wave>>1); W_hh slice in LDS (64KB,
// conflict-free ds_read_b128); tagged {f16x2, step} u64 words, parity double-buffered.
//
// R8 post-mortem (600s HANG): the sc0-load poll bet that sc0 bypasses L1 on loads;
// if not, the tight poll loop re-reads a never-evicted stale L1 line forever. Fix:
//  * consumer poll = atomic CAS(0->0) at WORKGROUP scope: atomic RMWs execute in the
//    L2 ALUs -- architecturally cannot be served by L1 -- and workgroup scope carries
//    no sc1, so the CAS is serviced by the LOCAL XCD L2 (~150-250cy RTT).
//    (Not fetch_add(0)/fetch_or(0): LLVM folds idempotent RMWs into atomic loads.)
//  * producer publish = plain 8B store: CDNA vector L1 is write-through, so the store
//    reaches the shared XCD L2 unconditionally; 8B aligned = indivisible vs the CAS.
//  * precondition (all 8 partner WGs on ONE XCD) verified at runtime via
//    s_getreg(HW_REG_XCC_ID) [m09] exchanged through the R5-proven agent-atomic
//    fabric; all 8 WGs see the same 8 values -> identical `fast`. fast=false ->
//    exact R7 agent-atomic behavior (1750us known-good). No mixed-mode paths.
__device__ __forceinline__ float dot2(uint wp, uint hp, float acc) {
#if __has_builtin(__builtin_amdgcn_fdot2)
  return __builtin_amdgcn_fdot2(__builtin_bit_cast(f16x2, wp),
                                __builtin_bit_cast(f16x2, hp), acc, false);
#else
  f16x2 a = __builtin_bit_cast(f16x2, wp);
  f16x2 b = __builtin_bit_cast(f16x2, hp);
  return acc + (float)a.x * (float)b.x + (float)a.y * (float)b.y;
#endif
}

__device__ __forceinline__ float sigm(float v) { return 1.f / (1.f + __expf(-v)); }
__device__ __forceinline__ float tanh_(float v) { return 1.f - 2.f / (__expf(2.f * v) + 1.f); }
__device__ __forceinline__ float f16u(ushort u) { return (float)__builtin_bit_cast(f16, u); }

__global__ __launch_bounds__(512)
void k_lstm(const int* __restrict__ evs,
            const f16* __restrict__ proj,
            const uint* __restrict__ whh_t,
            u64* hglob,                 // [32 batch][2 slot][128 pair] tagged words
            uint* xcd_map,              // [256] xcc_id+1 per WG (zeroed per launch)
            float* __restrict__ out) {
  int bid = blockIdx.x;
  int b = bid & 31, q = bid >> 5;
  int t = threadIdx.x;
  int v = t >> 6, l = t & 63;
  int kq = v >> 1;                     // k-quarter, wave-uniform
  int rid = (v & 1) * 64 + l;          // local gate-row 0..127 (= g*32 + jj)
  int rowg = (rid >> 5) * 256 + q * 32 + (rid & 31);

  __shared__ uint4 wlds[8 * 512];      // 64 KiB weights
  __shared__ float pl[2][4][128];      // partials [parity][kq][rid] -- conflict-free

  // ---- stage W_hh slice into LDS
  {
    const uint* wb = whh_t + (kq * 32) * G4 + rowg;
#pragma unroll
    for (int i4 = 0; i4 < 8; ++i4) {
      uint4 wv;
      wv.x = wb[(4 * i4 + 0) * G4];
      wv.y = wb[(4 * i4 + 1) * G4];
      wv.z = wb[(4 * i4 + 2) * G4];
      wv.w = wb[(4 * i4 + 3) * G4];
      wlds[i4 * 512 + t] = wv;
    }
  }

  // ---- XCD placement check (one-time; agent-atomic fabric, same liveness as the
  // R5-R7 main loops which require the same 8-WG co-residency and always completed).
  uint xid;
  asm volatile("s_getreg_b32 %0, hwreg(HW_REG_XCC_ID)" : "=s"(xid));
  if (t == 0)
    __hip_atomic_store(&xcd_map[bid], xid + 1u, __ATOMIC_RELAXED, __HIP_MEMORY_SCOPE_AGENT);
  uint e = 0;
  if (l < 8) {
    const uint* mp = &xcd_map[l * 32 + b];
    do {
      e = __hip_atomic_load(mp, __ATOMIC_RELAXED, __HIP_MEMORY_SCOPE_AGENT);
    } while (e == 0);
  }
  uint e0 = (uint)__builtin_amdgcn_readfirstlane((int)e);
  bool fast = __all((l >= 8) || (e == e0));

  __syncthreads();                     // wlds staged

  u64* hb = hglob + b * 256;
  const int* ev = evs + b * SEQ;

  // t<32 carries x for dim q*32+t, all 4 gates, one step ahead (gate-packed proj)
  float x0 = 0.f, x1 = 0.f, x2 = 0.f, x3 = 0.f;
  if (t < 32) {
    ushort4 xv = *(const ushort4*)(proj + (long)ev[0] * G4 + (q * 32 + t) * 4);
    x0 = f16u(xv.x); x1 = f16u(xv.y); x2 = f16u(xv.z); x3 = f16u(xv.w);
  }

  float c = 0.f;

  for (int step = 0; step < SEQ; ++step) {
    // (1) poll h_{step-1} (lanes 0..31 = readlane sources)
    int h0 = 0;
    if (step > 0 && l < 32) {
      u64* src = hb + ((step - 1) & 1) * 128 + kq * 32 + l;
      u64 val;
      if (fast) {
        // CAS(0->0): pure read serviced by the local XCD L2 (atomics bypass L1).
        do {
          u64 exp = 0ull;
          __hip_atomic_compare_exchange_strong(src, &exp, 0ull,
              __ATOMIC_RELAXED, __ATOMIC_RELAXED, __HIP_MEMORY_SCOPE_WORKGROUP);
          val = exp;
        } while ((uint)(val >> 32) != (uint)step);
      } else {
        do {
          val = __hip_atomic_load(src, __ATOMIC_RELAXED, __HIP_MEMORY_SCOPE_AGENT);
        } while ((uint)(val >> 32) != (uint)step);
      }
      h0 = (int)(uint)val;
    }

    // (2) matvec partial over pairs [kq*32,+32): LDS weights + readlane h
    float a0 = 0.f, a1 = 0.f, a2 = 0.f, a3 = 0.f;
#pragma unroll
    for (int i4 = 0; i4 < 8; ++i4) {
      uint4 wv = wlds[i4 * 512 + t];
      a0 = dot2(wv.x, (uint)__builtin_amdgcn_readlane(h0, 4 * i4 + 0), a0);
      a1 = dot2(wv.y, (uint)__builtin_amdgcn_readlane(h0, 4 * i4 + 1), a1);
      a2 = dot2(wv.z, (uint)__builtin_amdgcn_readlane(h0, 4 * i4 + 2), a2);
      a3 = dot2(wv.w, (uint)__builtin_amdgcn_readlane(h0, 4 * i4 + 3), a3);
    }
    pl[step & 1][kq][rid] = (a0 + a1) + (a2 + a3);   // lanes stride-1 -> no conflicts

    // (3) prefetch next step's x (one 8B load, off the critical chain)
    float n0 = 0.f, n1 = 0.f, n2 = 0.f, n3 = 0.f;
    if (t < 32 && step + 1 < SEQ) {
      ushort4 xv = *(const ushort4*)(proj + (long)ev[step + 1] * G4 + (q * 32 + t) * 4);
      n0 = f16u(xv.x); n1 = f16u(xv.y); n2 = f16u(xv.z); n3 = f16u(xv.w);
    }

    __syncthreads();                   // the only barrier per step

    // (4) finale on t<32: reduce + activations + publish (publish FIRST), output
    if (t < 32) {
      const float (*pp)[128] = pl[step & 1];
      float s0 = (pp[0][t]      + pp[1][t])      + (pp[2][t]      + pp[3][t])      + x0;
      float s1 = (pp[0][32 + t] + pp[1][32 + t]) + (pp[2][32 + t] + pp[3][32 + t]) + x1;
      float s2 = (pp[0][64 + t] + pp[1][64 + t]) + (pp[2][64 + t] + pp[3][64 + t]) + x2;
      float s3 = (pp[0][96 + t] + pp[1][96 + t]) + (pp[2][96 + t] + pp[3][96 + t]) + x3;
      float iv = sigm(s0), fv = sigm(s1), gv = tanh_(s2), ov = sigm(s3);
      c = fv * c + iv * gv;
      float hval = ov * tanh_(c);
      float hA = __shfl(hval, 2 * (t & 15));
      float hB = __shfl(hval, 2 * (t & 15) + 1);
      if (t < 16) {
        f16x2 pk; pk.x = (f16)hA; pk.y = (f16)hB;
        u64 val = (u64)__builtin_bit_cast(uint, pk) | ((u64)(uint)(step + 1) << 32);
        u64* dst = hb + (step & 1) * 128 + q * 16 + t;
        if (fast) {
          *(volatile u64*)dst = val;   // write-through L1 -> lands in shared XCD L2
        } else {
          __hip_atomic_store(dst, val, __ATOMIC_RELAXED, __HIP_MEMORY_SCOPE_AGENT);
        }
      }
      out[(step * BATCH + b) * HID + q * 32 + t] = hval;
    }
    x0 = n0; x1 = n1; x2 = n2; x3 = n3;
    // pl hazard: reads of pl[s&1] precede barrier(s+1); next write of pl[s&1]
    // is after barrier(s+1). Safe with one barrier.
  }
}

extern "C" void kernel_launch(void* const* d_in, const int* in_sizes, int n_in,
                              void* d_out, int out_size, void* d_ws, size_t ws_size,
                              hipStream_t stream) {
  (void)n_in; (void)out_size; (void)ws_size;
  const int* evs = (const int*)d_in[0];
  const int* anc = (const int*)d_in[1];
  const float* weight = (const float*)d_in[2];
  const float* emb = (const float*)d_in[3];
  const float* wih = (const float*)d_in[4];
  const float* whh = (const float*)d_in[5];
  const float* bih = (const float*)d_in[6];
  const float* bhh = (const float*)d_in[7];
  int D = in_sizes[1] / N_TYPES;

  char* ws = (char*)d_ws;
  f16* path = (f16*)(ws);                       // 10000*256*2 = 5,120,000 (dead after k_gemm)
  f16* wih_h = (f16*)(ws + 5242880);            // 524,288
  uint* whh_t = (uint*)(ws + 5767168);          // 524,288
  float* bias = (float*)(ws + 6291456);         // 4,096
  f16* proj = (f16*)(ws + 6295552);             // 10000*1024*2 = 20,480,000 (gate-packed)
  u64* hglob = (u64*)(ws + 26775552);           // 32*2*128*8 = 65,536
  uint* xcd_map = (uint*)(ws + 26841088);       // 1,024 (contiguous after hglob)
  float* out = (float*)d_out;

  k_conv<<<1024, 256, 0, stream>>>(wih, whh, bih, bhh, wih_h, whh_t, bias);
  k_path<<<N_TYPES, 256, 0, stream>>>(anc, weight, emb, D, path);
  k_gemm<<<dim3(79, 8), 256, 0, stream>>>(path, wih_h, bias, proj);
  hipMemsetAsync(hglob, 0, 65536 + 1024, stream);   // zero tags + xcd_map (replay-safe)
  k_lstm<<<256, 512, 0, stream>>>(evs, proj, whh_t, hglob, xcd_map, out);
}

// Round 11
// 1895.963 us; speedup vs baseline: 2.2252x; 2.2252x over previous
//
#include <hip/hip_runtime.h>

typedef unsigned int uint;
typedef unsigned long long u64;
typedef _Float16 f16;
typedef _Float16 f16x2 __attribute__((ext_vector_type(2)));
typedef _Float16 f16x8 __attribute__((ext_vector_type(8)));
typedef float f32x4 __attribute__((ext_vector_type(4)));

#define N_TYPES 10000
#define HID 256
#define G4 1024
#define BATCH 32
#define SEQ 1024

// ---------------- K1: path table: path[n][h] = sum_d cumw_d * emb[anc[n,d]][h]
__global__ void k_path(const int* __restrict__ anc, const float* __restrict__ weight,
                       const float* __restrict__ emb, int D, f16* __restrict__ path) {
  int n = blockIdx.x;
  int h = threadIdx.x;
  float acc = 0.f, cw = 1.f;
  for (int d = 0; d < D; ++d) {
    int a = anc[n * D + d];
    if (a < 0) break;
    acc += cw * emb[a * HID + h];
    cw *= weight[a];
  }
  path[n * HID + h] = (f16)acc;
}

// ---------------- K0: convert W_ih -> f16, W_hh -> transposed packed f16 pairs, bias = b_ih+b_hh
// whh_t layout: [128 kpair][1024 row] u32 (pair = f16 k, k+1 of row)
__global__ void k_conv(const float* __restrict__ wih, const float* __restrict__ whh,
                       const float* __restrict__ bih, const float* __restrict__ bhh,
                       f16* __restrict__ wih_h, uint* __restrict__ whh_t,
                       float* __restrict__ bias) {
  int i = blockIdx.x * 256 + threadIdx.x;   // 262144 threads
  wih_h[i] = (f16)wih[i];
  if (i < G4 * 128) {
    int row = i >> 7, p = i & 127;
    f16x2 v;
    v.x = (f16)whh[row * HID + 2 * p];
    v.y = (f16)whh[row * HID + 2 * p + 1];
    whh_t[p * G4 + row] = __builtin_bit_cast(uint, v);
  }
  if (i < G4) bias[i] = bih[i] + bhh[i];
}

// ---------------- K2: proj[n][r] = sum_k path[n][k]*W_ih[r][k] + bias[r]   (M=10000,N=1024,K=256)
#define BM 128
#define BN 128
#define BK 64
#define LPAD 72
__global__ __launch_bounds__(256) void k_gemm(const f16* __restrict__ A,
                                              const f16* __restrict__ Bw,
                                              const float* __restrict__ bias,
                                              f16* __restrict__ C) {
  __shared__ f16 sA[BM][LPAD];
  __shared__ f16 sB[BN][LPAD];
  int m0 = blockIdx.x * BM, n0 = blockIdx.y * BN;
  int tid = threadIdx.x;
  int wid = tid >> 6, lane = tid & 63;
  int wm = wid & 1, wn = wid >> 1;
  f32x4 acc[4][4] = {};
  for (int k0 = 0; k0 < 256; k0 += BK) {
    __syncthreads();
    int r = tid >> 3, kc = (tid & 7) * 8;
    for (int i = 0; i < 4; ++i) {
      int row = r + 32 * i;
      int gm = m0 + row;
      uint4 va = make_uint4(0u, 0u, 0u, 0u);
      if (gm < N_TYPES) va = *(const uint4*)&A[gm * 256 + k0 + kc];
      *(uint4*)&sA[row][kc] = va;
      uint4 vb = *(const uint4*)&Bw[(n0 + row) * 256 + k0 + kc];
      *(uint4*)&sB[row][kc] = vb;
    }
    __syncthreads();
#pragma unroll
    for (int ks = 0; ks < 2; ++ks) {
      f16x8 af[4], bf[4];
      int kk = ks * 32 + (lane >> 4) * 8;
#pragma unroll
      for (int mt = 0; mt < 4; ++mt)
        af[mt] = *(const f16x8*)&sA[wm * 64 + mt * 16 + (lane & 15)][kk];
#pragma unroll
      for (int nt = 0; nt < 4; ++nt)
        bf[nt] = *(const f16x8*)&sB[wn * 64 + nt * 16 + (lane & 15)][kk];
#pragma unroll
      for (int mt = 0; mt < 4; ++mt)
#pragma unroll
        for (int nt = 0; nt < 4; ++nt)
          acc[mt][nt] = __builtin_amdgcn_mfma_f32_16x16x32_f16(af[mt], bf[nt], acc[mt][nt], 0, 0, 0);
    }
  }
#pragma unroll
  for (int mt = 0; mt < 4; ++mt)
#pragma unroll
    for (int nt = 0; nt < 4; ++nt)
#pragma unroll
      for (int qq = 0; qq < 4; ++qq) {
        int row = m0 + wm * 64 + mt * 16 + (lane >> 4) * 4 + qq;
        int col = n0 + wn * 64 + nt * 16 + (lane & 15);
        if (row < N_TYPES) C[row * G4 + col] = (f16)(acc[mt][nt][qq] + bias[col]);
      }
}

// ---------------- K3: LSTM recurrence, v10 = R5 (1593us, best-measured) + SSA-safe
// 2-slot pipelined poll + publish-before-out.
//
// R10 post-mortem: hard-clobbered v20-23 poll crashed -- a dangling in-flight load
// retires AFTER the asm block and overwrites whatever the compiler reallocated into
// those regs. This version keeps every poll register in SSA form:
//  * slots are C u64 variables; loads issue via asm "=v"(slot);
//  * each check: asm("s_waitcnt vmcnt(1)" : "+v"(slot)) ties the wait to the slot's
//    dataflow (no compiler hoisting), waits only the OLDER outstanding load;
//  * whole-wave exit decided by __all() in C;
//  * on exit, the other slot's load may still be in flight -- its target register
//    is kept LIVE until a keep-alive asm after barrier [1], so the compiler cannot
//    reuse it, and the retire lands harmlessly. The dangling op is always the
//    OLDEST outstanding vmem op, so any compiler-counted vmcnt(N) retires it first
//    (conservative). Barrier [1]'s vmcnt(0) drain retires it under the dot2s.
// Fabric unchanged from R5: tagged {f16x2, step} u64 words, RELAXED agent atomics
// for publish (R8 sc0-poll hung; R9 CAS-poll caused a 2.2GB HBM write storm).
__device__ __forceinline__ float dot2(uint wp, uint hp, float acc) {
#if __has_builtin(__builtin_amdgcn_fdot2)
  return __builtin_amdgcn_fdot2(__builtin_bit_cast(f16x2, wp),
                                __builtin_bit_cast(f16x2, hp), acc, false);
#else
  f16x2 a = __builtin_bit_cast(f16x2, wp);
  f16x2 b = __builtin_bit_cast(f16x2, hp);
  return acc + (float)a.x * (float)b.x + (float)a.y * (float)b.y;
#endif
}

__device__ __forceinline__ float sigm(float v) { return 1.f / (1.f + __expf(-v)); }
__device__ __forceinline__ float tanh_(float v) { return 1.f - 2.f / (__expf(2.f * v) + 1.f); }

__global__ __launch_bounds__(512, 2)
void k_lstm(const int* __restrict__ evs,
            const f16* __restrict__ proj,
            const uint* __restrict__ whh_t,
            u64* hglob,                 // [32 batch][2 slot][128 pair] tagged words
            float* __restrict__ out) {
  int bid = blockIdx.x;
  int b = bid & 31, q = bid >> 5;      // 8 WGs of batch b share bid%8 -> same XCD
  int t = threadIdx.x;
  int v = t >> 6, l = t & 63;
  int kq = v >> 1;                     // k-quarter, wave-uniform (readlane needs this)
  int rid = (v & 1) * 64 + l;          // local gate-row 0..127
  int rowg = (rid >> 5) * 256 + q * 32 + (rid & 31);   // global gate-row

  __shared__ float pl[512];
  __shared__ float rt[128];

  uint w[32];
#pragma unroll
  for (int i = 0; i < 32; ++i) w[i] = whh_t[(kq * 32 + i) * G4 + rowg];

  u64* hb = hglob + b * 256;           // [2][128]
  const int* ev = evs + b * SEQ;

  // reducer thread t<128 handles row rid=t; x = proj[e][rrow]
  int rrow = (t >> 5) * 256 + q * 32 + (t & 31);
  float x_cur = 0.f, x_nxt = 0.f;
  if (t < 128) x_cur = (float)proj[(long)ev[0] * G4 + rrow];

  float c = 0.f;

  for (int step = 0; step < SEQ; ++step) {
    // ---- gather h_{step-1}: lanes 0..31 (readlane sources), 2-slot pipelined poll
    int h0 = 0;
    u64 s0 = 0, s1 = 0;                // poll slots; stay live past barrier [1]
    if (step > 0) {
      if (l < 32) {
        const u64* src = hb + ((step - 1) & 1) * 128 + kq * 32 + l;
        uint tag = (uint)step;
        // issue both slots, phase-shifted ~384cy -> check cadence ~450cy (vs ~900)
        asm volatile(
            "global_load_dwordx2 %0, %2, off sc0 sc1\n\t"
            "s_sleep 6\n\t"
            "global_load_dwordx2 %1, %2, off sc0 sc1"
            : "=v"(s0), "=v"(s1) : "v"(src) : "memory");
        while (true) {
          asm volatile("s_waitcnt vmcnt(1)" : "+v"(s0));          // s0 retired
          if (__all((uint)(s0 >> 32) == tag)) { h0 = (int)(uint)s0; break; }
          asm volatile("global_load_dwordx2 %0, %1, off sc0 sc1"
                       : "=v"(s0) : "v"(src) : "memory");
          asm volatile("s_waitcnt vmcnt(1)" : "+v"(s1));          // s1 retired
          if (__all((uint)(s1 >> 32) == tag)) { h0 = (int)(uint)s1; break; }
          asm volatile("global_load_dwordx2 %0, %1, off sc0 sc1"
                       : "=v"(s1) : "v"(src) : "memory");
        }
      }
    }

    // ---- partial dot over pairs [kq*32, kq*32+32)
    float a0 = 0.f, a1 = 0.f, a2 = 0.f, a3 = 0.f;
#pragma unroll
    for (int i = 0; i < 32; i += 4) {
      a0 = dot2(w[i + 0], (uint)__builtin_amdgcn_readlane(h0, i + 0), a0);
      a1 = dot2(w[i + 1], (uint)__builtin_amdgcn_readlane(h0, i + 1), a1);
      a2 = dot2(w[i + 2], (uint)__builtin_amdgcn_readlane(h0, i + 2), a2);
      a3 = dot2(w[i + 3], (uint)__builtin_amdgcn_readlane(h0, i + 3), a3);
    }
    pl[kq * 128 + rid] = (a0 + a1) + (a2 + a3);

    // prefetch next step's x while everyone converges (full step of latency cover)
    if (t < 128 && step + 1 < SEQ) x_nxt = (float)proj[(long)ev[step + 1] * G4 + rrow];

    __syncthreads();                                   // [1] partials visible
                                                       //     (vmcnt(0) drain here also
                                                       //      retires any dangling poll load)
    asm volatile("" :: "v"(s0), "v"(s1));              // slots live until HERE
    if (t < 128) rt[t] = pl[t] + pl[128 + t] + pl[256 + t] + pl[384 + t] + x_cur;
    __syncthreads();                                   // [2] row sums visible

    if (t < 32) {
      float gi = rt[t], gf = rt[32 + t], gg = rt[64 + t], go = rt[96 + t];
      float iv = sigm(gi), fv = sigm(gf), gv = tanh_(gg), ov = sigm(go);
      c = fv * c + iv * gv;
      float hval = ov * tanh_(c);
      float hA = __shfl(hval, 2 * (t & 15));
      float hB = __shfl(hval, 2 * (t & 15) + 1);
      if (t < 16) {                                    // publish FIRST (critical path)
        f16x2 pk; pk.x = (f16)hA; pk.y = (f16)hB;
        uint pku = __builtin_bit_cast(uint, pk);
        u64 val = (u64)pku | ((u64)(uint)(step + 1) << 32);
        __hip_atomic_store(hb + (step & 1) * 128 + q * 16 + t, val,
                           __ATOMIC_RELAXED, __HIP_MEMORY_SCOPE_AGENT);
      }
      out[(step * BATCH + b) * HID + q * 32 + t] = hval;   // output off the sync path
    }
    x_cur = x_nxt;
    // no third barrier: next-step pl/rt writes are gated by barrier [1] of step+1,
    // which every thread reaches only after this step's reads are done.
  }
}

extern "C" void kernel_launch(void* const* d_in, const int* in_sizes, int n_in,
                              void* d_out, int out_size, void* d_ws, size_t ws_size,
                              hipStream_t stream) {
  (void)n_in; (void)out_size; (void)ws_size;
  const int* evs = (const int*)d_in[0];
  const int* anc = (const int*)d_in[1];
  const float* weight = (const float*)d_in[2];
  const float* emb = (const float*)d_in[3];
  const float* wih = (const float*)d_in[4];
  const float* whh = (const float*)d_in[5];
  const float* bih = (const float*)d_in[6];
  const float* bhh = (const float*)d_in[7];
  int D = in_sizes[1] / N_TYPES;

  char* ws = (char*)d_ws;
  f16* path = (f16*)(ws);                       // 10000*256*2 = 5,120,000 (dead after k_gemm)
  f16* wih_h = (f16*)(ws + 5242880);            // 524,288
  uint* whh_t = (uint*)(ws + 5767168);          // 524,288
  float* bias = (float*)(ws + 6291456);         // 4,096
  f16* proj = (f16*)(ws + 6295552);             // 10000*1024*2 = 20,480,000
  u64* hglob = (u64*)(ws + 26775552);           // 32*2*128*8 = 65,536
  float* out = (float*)d_out;

  k_conv<<<1024, 256, 0, stream>>>(wih, whh, bih, bhh, wih_h, whh_t, bias);
  k_path<<<N_TYPES, 256, 0, stream>>>(anc, weight, emb, D, path);
  k_gemm<<<dim3(79, 8), 256, 0, stream>>>(path, wih_h, bias, proj);
  hipMemsetAsync(hglob, 0, 32 * 2 * 128 * 8, stream);   // zero tags (replay-safe)
  k_lstm<<<256, 512, 0, stream>>>(evs, proj, whh_t, hglob, out);
}

// Round 12
// 1789.339 us; speedup vs baseline: 2.3578x; 1.0596x over previous
//
#include <hip/hip_runtime.h>

typedef unsigned int uint;
typedef unsigned long long u64;
typedef _Float16 f16;
typedef _Float16 f16x2 __attribute__((ext_vector_type(2)));
typedef _Float16 f16x8 __attribute__((ext_vector_type(8)));
typedef float f32x4 __attribute__((ext_vector_type(4)));

#define N_TYPES 10000
#define HID 256
#define G4 1024
#define BATCH 32
#define SEQ 1024

// ---------------- K1: path table: path[n][h] = sum_d cumw_d * emb[anc[n,d]][h]
__global__ void k_path(const int* __restrict__ anc, const float* __restrict__ weight,
                       const float* __restrict__ emb, int D, f16* __restrict__ path) {
  int n = blockIdx.x;
  int h = threadIdx.x;
  float acc = 0.f, cw = 1.f;
  for (int d = 0; d < D; ++d) {
    int a = anc[n * D + d];
    if (a < 0) break;
    acc += cw * emb[a * HID + h];
    cw *= weight[a];
  }
  path[n * HID + h] = (f16)acc;
}

// ---------------- K0: convert W_ih -> f16, W_hh -> transposed packed f16 pairs, bias = b_ih+b_hh
// whh_t layout: [128 kpair][1024 row] u32 (pair = f16 k, k+1 of row)
__global__ void k_conv(const float* __restrict__ wih, const float* __restrict__ whh,
                       const float* __restrict__ bih, const float* __restrict__ bhh,
                       f16* __restrict__ wih_h, uint* __restrict__ whh_t,
                       float* __restrict__ bias) {
  int i = blockIdx.x * 256 + threadIdx.x;   // 262144 threads
  wih_h[i] = (f16)wih[i];
  if (i < G4 * 128) {
    int row = i >> 7, p = i & 127;
    f16x2 v;
    v.x = (f16)whh[row * HID + 2 * p];
    v.y = (f16)whh[row * HID + 2 * p + 1];
    whh_t[p * G4 + row] = __builtin_bit_cast(uint, v);
  }
  if (i < G4) bias[i] = bih[i] + bhh[i];
}

// ---------------- K2: proj[n][r] = sum_k path[n][k]*W_ih[r][k] + bias[r]   (M=10000,N=1024,K=256)
#define BM 128
#define BN 128
#define BK 64
#define LPAD 72
__global__ __launch_bounds__(256) void k_gemm(const f16* __restrict__ A,
                                              const f16* __restrict__ Bw,
                                              const float* __restrict__ bias,
                                              f16* __restrict__ C) {
  __shared__ f16 sA[BM][LPAD];
  __shared__ f16 sB[BN][LPAD];
  int m0 = blockIdx.x * BM, n0 = blockIdx.y * BN;
  int tid = threadIdx.x;
  int wid = tid >> 6, lane = tid & 63;
  int wm = wid & 1, wn = wid >> 1;
  f32x4 acc[4][4] = {};
  for (int k0 = 0; k0 < 256; k0 += BK) {
    __syncthreads();
    int r = tid >> 3, kc = (tid & 7) * 8;
    for (int i = 0; i < 4; ++i) {
      int row = r + 32 * i;
      int gm = m0 + row;
      uint4 va = make_uint4(0u, 0u, 0u, 0u);
      if (gm < N_TYPES) va = *(const uint4*)&A[gm * 256 + k0 + kc];
      *(uint4*)&sA[row][kc] = va;
      uint4 vb = *(const uint4*)&Bw[(n0 + row) * 256 + k0 + kc];
      *(uint4*)&sB[row][kc] = vb;
    }
    __syncthreads();
#pragma unroll
    for (int ks = 0; ks < 2; ++ks) {
      f16x8 af[4], bf[4];
      int kk = ks * 32 + (lane >> 4) * 8;
#pragma unroll
      for (int mt = 0; mt < 4; ++mt)
        af[mt] = *(const f16x8*)&sA[wm * 64 + mt * 16 + (lane & 15)][kk];
#pragma unroll
      for (int nt = 0; nt < 4; ++nt)
        bf[nt] = *(const f16x8*)&sB[wn * 64 + nt * 16 + (lane & 15)][kk];
#pragma unroll
      for (int mt = 0; mt < 4; ++mt)
#pragma unroll
        for (int nt = 0; nt < 4; ++nt)
          acc[mt][nt] = __builtin_amdgcn_mfma_f32_16x16x32_f16(af[mt], bf[nt], acc[mt][nt], 0, 0, 0);
    }
  }
#pragma unroll
  for (int mt = 0; mt < 4; ++mt)
#pragma unroll
    for (int nt = 0; nt < 4; ++nt)
#pragma unroll
      for (int qq = 0; qq < 4; ++qq) {
        int row = m0 + wm * 64 + mt * 16 + (lane >> 4) * 4 + qq;
        int col = n0 + wn * 64 + nt * 16 + (lane & 15);
        if (row < N_TYPES) C[row * G4 + col] = (f16)(acc[mt][nt][qq] + bias[col]);
      }
}

// ---------------- K3: LSTM recurrence, v11 = R5 + DEDICATED POLLER WAVES.
// R5 skeleton (1593us best): 256 WGs of 512 thr, bid=q*32+b; WG q owns dims
// [q*32,+32) x 4 gates = 128 rows, k-split 4 (kq=v>>1); tagged {f16x2,step} u64
// agent-relaxed fabric; per-thread w[32] (RA demotes to per-step L2 loads; proven
// fastest of all weight-supply variants R5-R7).
//
// R11 post-mortem: vmcnt is PER-WAVE -- a poll's vmcnt(1) in a wave that also has
// x-prefetch loads / out / publish stores outstanding serializes the poll against
// those acks. Fix (this version):
//  * waves 6,7 = dedicated pollers (1 word/lane, 128 words): NO other vmem ops ->
//    vmcnt(1) sees exactly the 2 pipelined poll loads -> clean ~450cy cadence
//    (R11's SSA-safe asm, proven correct).
//  * discovered payloads -> hlds[2][128] (LDS); matvec h comes from LDS broadcast
//    reads (ds_read_b128, wave-uniform addr = conflict-free) -- no readlanes.
//  * barrier A = RAW s_barrier + manual lgkmcnt(0): no vmcnt(0) drain, so the
//    dangling 2nd poll slot doesn't stall the barrier; its regs stay live until
//    after barrier [1] (R10 crash lesson), where __syncthreads' drain retires it.
__device__ __forceinline__ float dot2(uint wp, uint hp, float acc) {
#if __has_builtin(__builtin_amdgcn_fdot2)
  return __builtin_amdgcn_fdot2(__builtin_bit_cast(f16x2, wp),
                                __builtin_bit_cast(f16x2, hp), acc, false);
#else
  f16x2 a = __builtin_bit_cast(f16x2, wp);
  f16x2 b = __builtin_bit_cast(f16x2, hp);
  return acc + (float)a.x * (float)b.x + (float)a.y * (float)b.y;
#endif
}

__device__ __forceinline__ float sigm(float v) { return 1.f / (1.f + __expf(-v)); }
__device__ __forceinline__ float tanh_(float v) { return 1.f - 2.f / (__expf(2.f * v) + 1.f); }

__global__ __launch_bounds__(512, 2)
void k_lstm(const int* __restrict__ evs,
            const f16* __restrict__ proj,
            const uint* __restrict__ whh_t,
            u64* hglob,                 // [32 batch][2 slot][128 pair] tagged words
            float* __restrict__ out) {
  int bid = blockIdx.x;
  int b = bid & 31, q = bid >> 5;
  int t = threadIdx.x;
  int v = t >> 6, l = t & 63;
  int kq = v >> 1;                     // k-quarter for matvec (all 8 waves)
  int rid = (v & 1) * 64 + l;          // local gate-row 0..127
  int rowg = (rid >> 5) * 256 + q * 32 + (rid & 31);   // global gate-row

  __shared__ float pl[512];
  __shared__ float rt[128];
  __shared__ uint hlds[2][128];        // discovered h payloads (packed f16 pairs)

  uint w[32];
#pragma unroll
  for (int i = 0; i < 32; ++i) w[i] = whh_t[(kq * 32 + i) * G4 + rowg];

  u64* hb = hglob + b * 256;           // [2][128]
  const int* ev = evs + b * SEQ;

  // reducer thread t<128 handles row rid=t; x = proj[e][rrow]  (waves 0-1 only)
  int rrow = (t >> 5) * 256 + q * 32 + (t & 31);
  float x_cur = 0.f, x_nxt = 0.f;
  if (t < 128) x_cur = (float)proj[(long)ev[0] * G4 + rrow];

  float c = 0.f;

  for (int step = 0; step < SEQ; ++step) {
    // ---- (P) poll phase: waves 6,7 only; 1 word per lane, clean vmem counters
    u64 s0 = 0, s1 = 0;                // poll slots; live until after barrier [1]
    if (step > 0 && v >= 6) {
      int pr = (v - 6) * 64 + l;       // pair index 0..127
      const u64* src = hb + ((step - 1) & 1) * 128 + pr;
      uint tag = (uint)step;
      u64 val;
      asm volatile(
          "global_load_dwordx2 %0, %2, off sc0 sc1\n\t"
          "s_sleep 6\n\t"
          "global_load_dwordx2 %1, %2, off sc0 sc1"
          : "=v"(s0), "=v"(s1) : "v"(src) : "memory");
      while (true) {
        asm volatile("s_waitcnt vmcnt(1)" : "+v"(s0));          // s0 retired
        if (__all((uint)(s0 >> 32) == tag)) { val = s0; break; }
        asm volatile("global_load_dwordx2 %0, %1, off sc0 sc1"
                     : "=v"(s0) : "v"(src) : "memory");
        asm volatile("s_waitcnt vmcnt(1)" : "+v"(s1));          // s1 retired
        if (__all((uint)(s1 >> 32) == tag)) { val = s1; break; }
        asm volatile("global_load_dwordx2 %0, %1, off sc0 sc1"
                     : "=v"(s1) : "v"(src) : "memory");
      }
      hlds[(step - 1) & 1][pr] = (uint)val;
    }
    // barrier A: RAW s_barrier, lgkm drained (hlds writes visible), vmcnt NOT
    // drained (dangling poll slot stays in flight; regs s0/s1 kept live below).
    asm volatile("s_waitcnt lgkmcnt(0)" ::: "memory");
    __builtin_amdgcn_s_barrier();
    __builtin_amdgcn_sched_barrier(0);

    // ---- matvec partial over pairs [kq*32,+32): h from LDS broadcast
    float a0 = 0.f, a1 = 0.f, a2 = 0.f, a3 = 0.f;
    if (step > 0) {
      const uint4* hp4 = (const uint4*)&hlds[(step - 1) & 1][kq * 32];
#pragma unroll
      for (int i4 = 0; i4 < 8; ++i4) {
        uint4 h4 = hp4[i4];            // wave-uniform addr -> LDS broadcast
        a0 = dot2(w[4 * i4 + 0], h4.x, a0);
        a1 = dot2(w[4 * i4 + 1], h4.y, a1);
        a2 = dot2(w[4 * i4 + 2], h4.z, a2);
        a3 = dot2(w[4 * i4 + 3], h4.w, a3);
      }
    }
    pl[kq * 128 + rid] = (a0 + a1) + (a2 + a3);

    // prefetch next step's x (waves 0-1; off the poll path)
    if (t < 128 && step + 1 < SEQ) x_nxt = (float)proj[(long)ev[step + 1] * G4 + rrow];

    __syncthreads();                                   // [1] partials visible
    asm volatile("" :: "v"(s0), "v"(s1));              // poll slots live until HERE
    if (t < 128) rt[t] = pl[t] + pl[128 + t] + pl[256 + t] + pl[384 + t] + x_cur;
    __syncthreads();                                   // [2] row sums visible

    if (t < 32) {
      float gi = rt[t], gf = rt[32 + t], gg = rt[64 + t], go = rt[96 + t];
      float iv = sigm(gi), fv = sigm(gf), gv = tanh_(gg), ov = sigm(go);
      c = fv * c + iv * gv;
      float hval = ov * tanh_(c);
      float hA = __shfl(hval, 2 * (t & 15));
      float hB = __shfl(hval, 2 * (t & 15) + 1);
      if (t < 16) {                                    // publish FIRST (critical path)
        f16x2 pk; pk.x = (f16)hA; pk.y = (f16)hB;
        uint pku = __builtin_bit_cast(uint, pk);
        u64 val = (u64)pku | ((u64)(uint)(step + 1) << 32);
        __hip_atomic_store(hb + (step & 1) * 128 + q * 16 + t, val,
                           __ATOMIC_RELAXED, __HIP_MEMORY_SCOPE_AGENT);
      }
      out[(step * BATCH + b) * HID + q * 32 + t] = hval;   // off the sync path
    }
    x_cur = x_nxt;
    // hazards: hlds[(s-1)&1] written in poll(s) after poller passed [2] of s-1;
    // all matvec reads of that slot happened before [1] of s-1. pl/rt as R5.
  }
}

extern "C" void kernel_launch(void* const* d_in, const int* in_sizes, int n_in,
                              void* d_out, int out_size, void* d_ws, size_t ws_size,
                              hipStream_t stream) {
  (void)n_in; (void)out_size; (void)ws_size;
  const int* evs = (const int*)d_in[0];
  const int* anc = (const int*)d_in[1];
  const float* weight = (const float*)d_in[2];
  const float* emb = (const float*)d_in[3];
  const float* wih = (const float*)d_in[4];
  const float* whh = (const float*)d_in[5];
  const float* bih = (const float*)d_in[6];
  const float* bhh = (const float*)d_in[7];
  int D = in_sizes[1] / N_TYPES;

  char* ws = (char*)d_ws;
  f16* path = (f16*)(ws);                       // 10000*256*2 = 5,120,000 (dead after k_gemm)
  f16* wih_h = (f16*)(ws + 5242880);            // 524,288
  uint* whh_t = (uint*)(ws + 5767168);          // 524,288
  float* bias = (float*)(ws + 6291456);         // 4,096
  f16* proj = (f16*)(ws + 6295552);             // 10000*1024*2 = 20,480,000
  u64* hglob = (u64*)(ws + 26775552);           // 32*2*128*8 = 65,536
  float* out = (float*)d_out;

  k_conv<<<1024, 256, 0, stream>>>(wih, whh, bih, bhh, wih_h, whh_t, bias);
  k_path<<<N_TYPES, 256, 0, stream>>>(anc, weight, emb, D, path);
  k_gemm<<<dim3(79, 8), 256, 0, stream>>>(path, wih_h, bias, proj);
  hipMemsetAsync(hglob, 0, 32 * 2 * 128 * 8, stream);   // zero tags (replay-safe)
  k_lstm<<<256, 512, 0, stream>>>(evs, proj, whh_t, hglob, out);
}

// Round 13
// 1673.560 us; speedup vs baseline: 2.5209x; 1.0692x over previous
//
#include <hip/hip_runtime.h>

typedef unsigned int uint;
typedef unsigned long long u64;
typedef _Float16 f16;
typedef _Float16 f16x2 __attribute__((ext_vector_type(2)));
typedef _Float16 f16x8 __attribute__((ext_vector_type(8)));
typedef float f32x4 __attribute__((ext_vector_type(4)));

#define N_TYPES 10000
#define HID 256
#define G4 1024
#define BATCH 32
#define SEQ 1024

// ---------------- K1: path table: path[n][h] = sum_d cumw_d * emb[anc[n,d]][h]
__global__ void k_path(const int* __restrict__ anc, const float* __restrict__ weight,
                       const float* __restrict__ emb, int D, f16* __restrict__ path) {
  int n = blockIdx.x;
  int h = threadIdx.x;
  float acc = 0.f, cw = 1.f;
  for (int d = 0; d < D; ++d) {
    int a = anc[n * D + d];
    if (a < 0) break;
    acc += cw * emb[a * HID + h];
    cw *= weight[a];
  }
  path[n * HID + h] = (f16)acc;
}

// ---------------- K0: convert W_ih -> f16, W_hh -> transposed packed f16 pairs, bias = b_ih+b_hh
// whh_t layout: [128 kpair][1024 row] u32 (pair = f16 k, k+1 of row)
__global__ void k_conv(const float* __restrict__ wih, const float* __restrict__ whh,
                       const float* __restrict__ bih, const float* __restrict__ bhh,
                       f16* __restrict__ wih_h, uint* __restrict__ whh_t,
                       float* __restrict__ bias) {
  int i = blockIdx.x * 256 + threadIdx.x;   // 262144 threads
  wih_h[i] = (f16)wih[i];
  if (i < G4 * 128) {
    int row = i >> 7, p = i & 127;
    f16x2 v;
    v.x = (f16)whh[row * HID + 2 * p];
    v.y = (f16)whh[row * HID + 2 * p + 1];
    whh_t[p * G4 + row] = __builtin_bit_cast(uint, v);
  }
  if (i < G4) bias[i] = bih[i] + bhh[i];
}

// ---------------- K2: proj[n][r] = sum_k path[n][k]*W_ih[r][k] + bias[r]   (M=10000,N=1024,K=256)
#define BM 128
#define BN 128
#define BK 64
#define LPAD 72
__global__ __launch_bounds__(256) void k_gemm(const f16* __restrict__ A,
                                              const f16* __restrict__ Bw,
                                              const float* __restrict__ bias,
                                              f16* __restrict__ C) {
  __shared__ f16 sA[BM][LPAD];
  __shared__ f16 sB[BN][LPAD];
  int m0 = blockIdx.x * BM, n0 = blockIdx.y * BN;
  int tid = threadIdx.x;
  int wid = tid >> 6, lane = tid & 63;
  int wm = wid & 1, wn = wid >> 1;
  f32x4 acc[4][4] = {};
  for (int k0 = 0; k0 < 256; k0 += BK) {
    __syncthreads();
    int r = tid >> 3, kc = (tid & 7) * 8;
    for (int i = 0; i < 4; ++i) {
      int row = r + 32 * i;
      int gm = m0 + row;
      uint4 va = make_uint4(0u, 0u, 0u, 0u);
      if (gm < N_TYPES) va = *(const uint4*)&A[gm * 256 + k0 + kc];
      *(uint4*)&sA[row][kc] = va;
      uint4 vb = *(const uint4*)&Bw[(n0 + row) * 256 + k0 + kc];
      *(uint4*)&sB[row][kc] = vb;
    }
    __syncthreads();
#pragma unroll
    for (int ks = 0; ks < 2; ++ks) {
      f16x8 af[4], bf[4];
      int kk = ks * 32 + (lane >> 4) * 8;
#pragma unroll
      for (int mt = 0; mt < 4; ++mt)
        af[mt] = *(const f16x8*)&sA[wm * 64 + mt * 16 + (lane & 15)][kk];
#pragma unroll
      for (int nt = 0; nt < 4; ++nt)
        bf[nt] = *(const f16x8*)&sB[wn * 64 + nt * 16 + (lane & 15)][kk];
#pragma unroll
      for (int mt = 0; mt < 4; ++mt)
#pragma unroll
        for (int nt = 0; nt < 4; ++nt)
          acc[mt][nt] = __builtin_amdgcn_mfma_f32_16x16x32_f16(af[mt], bf[nt], acc[mt][nt], 0, 0, 0);
    }
  }
#pragma unroll
  for (int mt = 0; mt < 4; ++mt)
#pragma unroll
    for (int nt = 0; nt < 4; ++nt)
#pragma unroll
      for (int qq = 0; qq < 4; ++qq) {
        int row = m0 + wm * 64 + mt * 16 + (lane >> 4) * 4 + qq;
        int col = n0 + wn * 64 + nt * 16 + (lane & 15);
        if (row < N_TYPES) C[row * G4 + col] = (f16)(acc[mt][nt][qq] + bias[col]);
      }
}

// ---------------- K3: LSTM recurrence, v12 = R5 VERBATIM (1593us, best of 8 variants)
// with ONE change: publish via non-returning global_atomic_swap_x2.
//
// Evidence chain: R7 (weights->LDS), R11 (fast poll all waves), R12 (dedicated
// poller waves, ~450cy cadence) all LOST to R5 -> neither weight supply nor poll
// cadence is the binding term. The invariant was the plain-store publish: a plain
// store dirties the producer XCD's L2, and a remote poller must IF-miss + snoop
// that L2 (~2000+cy) before any poll can succeed. Fix: atomic swap executes AT the
// IF coherence point -- the tagged word lands IF-resident, remote polls become
// IF-hits (~600-900cy RTT). One swap per published word per step (16/WG) -- the
// opposite of R9's poll-side CAS storm (dozens/step/lane, 2.2GB writes).
__device__ __forceinline__ float dot2(uint wp, uint hp, float acc) {
#if __has_builtin(__builtin_amdgcn_fdot2)
  return __builtin_amdgcn_fdot2(__builtin_bit_cast(f16x2, wp),
                                __builtin_bit_cast(f16x2, hp), acc, false);
#else
  f16x2 a = __builtin_bit_cast(f16x2, wp);
  f16x2 b = __builtin_bit_cast(f16x2, hp);
  return acc + (float)a.x * (float)b.x + (float)a.y * (float)b.y;
#endif
}

__device__ __forceinline__ float sigm(float v) { return 1.f / (1.f + __expf(-v)); }
__device__ __forceinline__ float tanh_(float v) { return 1.f - 2.f / (__expf(2.f * v) + 1.f); }

__global__ __launch_bounds__(512, 2)
void k_lstm(const int* __restrict__ evs,
            const f16* __restrict__ proj,
            const uint* __restrict__ whh_t,
            u64* hglob,                 // [32 batch][2 slot][128 pair] tagged words
            float* __restrict__ out) {
  int bid = blockIdx.x;
  int b = bid & 31, q = bid >> 5;      // all 8 WGs of batch b: bid == b (mod 8)
  int t = threadIdx.x;
  int v = t >> 6, l = t & 63;
  int kq = v >> 1;                     // k-quarter, wave-uniform (readlane needs this)
  int rid = (v & 1) * 64 + l;          // local gate-row 0..127
  int rowg = (rid >> 5) * 256 + q * 32 + (rid & 31);   // global gate-row

  __shared__ float pl[512];
  __shared__ float rt[128];

  uint w[32];
#pragma unroll
  for (int i = 0; i < 32; ++i) w[i] = whh_t[(kq * 32 + i) * G4 + rowg];

  u64* hb = hglob + b * 256;           // [2][128]
  const int* ev = evs + b * SEQ;

  // reducer thread t<128 handles row rid=t; x = proj[e][rrow]
  int rrow = (t >> 5) * 256 + q * 32 + (t & 31);
  float x_cur = 0.f, x_nxt = 0.f;
  if (t < 128) x_cur = (float)proj[(long)ev[0] * G4 + rrow];

  float c = 0.f;

  for (int step = 0; step < SEQ; ++step) {
    // ---- gather h_{step-1}: only lanes 0..31 (they are the readlane sources)
    int h0 = 0;
    if (step > 0) {
      if (l < 32) {
        const u64* src = hb + ((step - 1) & 1) * 128 + kq * 32 + l;
        u64 val;
        do {
          val = __hip_atomic_load(src, __ATOMIC_RELAXED, __HIP_MEMORY_SCOPE_AGENT);
        } while ((uint)(val >> 32) != (uint)step);
        h0 = (int)(uint)val;
      }
    }

    // ---- partial dot over pairs [kq*32, kq*32+32)
    float a0 = 0.f, a1 = 0.f, a2 = 0.f, a3 = 0.f;
#pragma unroll
    for (int i = 0; i < 32; i += 4) {
      a0 = dot2(w[i + 0], (uint)__builtin_amdgcn_readlane(h0, i + 0), a0);
      a1 = dot2(w[i + 1], (uint)__builtin_amdgcn_readlane(h0, i + 1), a1);
      a2 = dot2(w[i + 2], (uint)__builtin_amdgcn_readlane(h0, i + 2), a2);
      a3 = dot2(w[i + 3], (uint)__builtin_amdgcn_readlane(h0, i + 3), a3);
    }
    pl[kq * 128 + rid] = (a0 + a1) + (a2 + a3);

    // prefetch next step's x while everyone converges (full step of latency cover)
    if (t < 128 && step + 1 < SEQ) x_nxt = (float)proj[(long)ev[step + 1] * G4 + rrow];

    __syncthreads();                                   // [1] partials visible
    if (t < 128) rt[t] = pl[t] + pl[128 + t] + pl[256 + t] + pl[384 + t] + x_cur;
    __syncthreads();                                   // [2] row sums visible

    if (t < 32) {
      float gi = rt[t], gf = rt[32 + t], gg = rt[64 + t], go = rt[96 + t];
      float iv = sigm(gi), fv = sigm(gf), gv = tanh_(gg), ov = sigm(go);
      c = fv * c + iv * gv;
      float hval = ov * tanh_(c);
      float hA = __shfl(hval, 2 * (t & 15));
      float hB = __shfl(hval, 2 * (t & 15) + 1);
      if (t < 16) {
        // publish FIRST (critical path): non-returning atomic swap carries the
        // tagged word straight to the IF coherence point (remote polls = IF hits).
        f16x2 pk; pk.x = (f16)hA; pk.y = (f16)hB;
        uint pku = __builtin_bit_cast(uint, pk);
        u64 val = (u64)pku | ((u64)(uint)(step + 1) << 32);
        (void)__hip_atomic_exchange(hb + (step & 1) * 128 + q * 16 + t, val,
                                    __ATOMIC_RELAXED, __HIP_MEMORY_SCOPE_AGENT);
      }
      out[(step * BATCH + b) * HID + q * 32 + t] = hval;   // off the sync path
    }
    x_cur = x_nxt;
    // no third barrier: next-step pl/rt writes are gated by barrier [1] of step+1,
    // which every thread reaches only after this step's reads are done.
  }
}

extern "C" void kernel_launch(void* const* d_in, const int* in_sizes, int n_in,
                              void* d_out, int out_size, void* d_ws, size_t ws_size,
                              hipStream_t stream) {
  (void)n_in; (void)out_size; (void)ws_size;
  const int* evs = (const int*)d_in[0];
  const int* anc = (const int*)d_in[1];
  const float* weight = (const float*)d_in[2];
  const float* emb = (const float*)d_in[3];
  const float* wih = (const float*)d_in[4];
  const float* whh = (const float*)d_in[5];
  const float* bih = (const float*)d_in[6];
  const float* bhh = (const float*)d_in[7];
  int D = in_sizes[1] / N_TYPES;

  char* ws = (char*)d_ws;
  f16* path = (f16*)(ws);                       // 10000*256*2 = 5,120,000 (dead after k_gemm)
  f16* wih_h = (f16*)(ws + 5242880);            // 524,288
  uint* whh_t = (uint*)(ws + 5767168);          // 524,288
  float* bias = (float*)(ws + 6291456);         // 4,096
  f16* proj = (f16*)(ws + 6295552);             // 10000*1024*2 = 20,480,000
  u64* hglob = (u64*)(ws + 26775552);           // 32*2*128*8 = 65,536
  float* out = (float*)d_out;

  k_conv<<<1024, 256, 0, stream>>>(wih, whh, bih, bhh, wih_h, whh_t, bias);
  k_path<<<N_TYPES, 256, 0, stream>>>(anc, weight, emb, D, path);
  k_gemm<<<dim3(79, 8), 256, 0, stream>>>(path, wih_h, bias, proj);
  hipMemsetAsync(hglob, 0, 32 * 2 * 128 * 8, stream);   // zero tags (replay-safe)
  k_lstm<<<256, 512, 0, stream>>>(evs, proj, whh_t, hglob, out);
}

// Round 14
// 1632.774 us; speedup vs baseline: 2.5839x; 1.0250x over previous
//
#include <hip/hip_runtime.h>

typedef unsigned int uint;
typedef unsigned long long u64;
typedef unsigned short ushort;
typedef _Float16 f16;
typedef _Float16 f16x2 __attribute__((ext_vector_type(2)));
typedef _Float16 f16x8 __attribute__((ext_vector_type(8)));
typedef float f32x4 __attribute__((ext_vector_type(4)));

#define N_TYPES 10000
#define HID 256
#define G4 1024
#define BATCH 32
#define SEQ 1024

// ---------------- K1: path table: path[n][h] = sum_d cumw_d * emb[anc[n,d]][h]
__global__ void k_path(const int* __restrict__ anc, const float* __restrict__ weight,
                       const float* __restrict__ emb, int D, f16* __restrict__ path) {
  int n = blockIdx.x;
  int h = threadIdx.x;
  float acc = 0.f, cw = 1.f;
  for (int d = 0; d < D; ++d) {
    int a = anc[n * D + d];
    if (a < 0) break;
    acc += cw * emb[a * HID + h];
    cw *= weight[a];
  }
  path[n * HID + h] = (f16)acc;
}

// ---------------- K0: convert W_ih -> f16, W_hh -> transposed packed f16 pairs, bias = b_ih+b_hh
// whh_t layout: [128 kpair][1024 row] u32 (pair = f16 k, k+1 of row)
__global__ void k_conv(const float* __restrict__ wih, const float* __restrict__ whh,
                       const float* __restrict__ bih, const float* __restrict__ bhh,
                       f16* __restrict__ wih_h, uint* __restrict__ whh_t,
                       float* __restrict__ bias) {
  int i = blockIdx.x * 256 + threadIdx.x;   // 262144 threads
  wih_h[i] = (f16)wih[i];
  if (i < G4 * 128) {
    int row = i >> 7, p = i & 127;
    f16x2 v;
    v.x = (f16)whh[row * HID + 2 * p];
    v.y = (f16)whh[row * HID + 2 * p + 1];
    whh_t[p * G4 + row] = __builtin_bit_cast(uint, v);
  }
  if (i < G4) bias[i] = bih[i] + bhh[i];
}

// ---------------- K2: proj[n][dim][gate] = path[n]@W_ih^T + b (gate-packed epilogue,
// R6/R7-proven): element (row=n, col=g*256+dim) stored at n*1024 + dim*4 + g so the
// LSTM x-gather is ONE 8B load.
#define BM 128
#define BN 128
#define BK 64
#define LPAD 72
__global__ __launch_bounds__(256) void k_gemm(const f16* __restrict__ A,
                                              const f16* __restrict__ Bw,
                                              const float* __restrict__ bias,
                                              f16* __restrict__ C) {
  __shared__ f16 sA[BM][LPAD];
  __shared__ f16 sB[BN][LPAD];
  int m0 = blockIdx.x * BM, n0 = blockIdx.y * BN;
  int tid = threadIdx.x;
  int wid = tid >> 6, lane = tid & 63;
  int wm = wid & 1, wn = wid >> 1;
  f32x4 acc[4][4] = {};
  for (int k0 = 0; k0 < 256; k0 += BK) {
    __syncthreads();
    int r = tid >> 3, kc = (tid & 7) * 8;
    for (int i = 0; i < 4; ++i) {
      int row = r + 32 * i;
      int gm = m0 + row;
      uint4 va = make_uint4(0u, 0u, 0u, 0u);
      if (gm < N_TYPES) va = *(const uint4*)&A[gm * 256 + k0 + kc];
      *(uint4*)&sA[row][kc] = va;
      uint4 vb = *(const uint4*)&Bw[(n0 + row) * 256 + k0 + kc];
      *(uint4*)&sB[row][kc] = vb;
    }
    __syncthreads();
#pragma unroll
    for (int ks = 0; ks < 2; ++ks) {
      f16x8 af[4], bf[4];
      int kk = ks * 32 + (lane >> 4) * 8;
#pragma unroll
      for (int mt = 0; mt < 4; ++mt)
        af[mt] = *(const f16x8*)&sA[wm * 64 + mt * 16 + (lane & 15)][kk];
#pragma unroll
      for (int nt = 0; nt < 4; ++nt)
        bf[nt] = *(const f16x8*)&sB[wn * 64 + nt * 16 + (lane & 15)][kk];
#pragma unroll
      for (int mt = 0; mt < 4; ++mt)
#pragma unroll
        for (int nt = 0; nt < 4; ++nt)
          acc[mt][nt] = __builtin_amdgcn_mfma_f32_16x16x32_f16(af[mt], bf[nt], acc[mt][nt], 0, 0, 0);
    }
  }
#pragma unroll
  for (int mt = 0; mt < 4; ++mt)
#pragma unroll
    for (int nt = 0; nt < 4; ++nt)
#pragma unroll
      for (int qq = 0; qq < 4; ++qq) {
        int row = m0 + wm * 64 + mt * 16 + (lane >> 4) * 4 + qq;
        int col = n0 + wn * 64 + nt * 16 + (lane & 15);
        int dim = col & 255, g = col >> 8;
        if (row < N_TYPES)
          C[row * G4 + dim * 4 + g] = (f16)(acc[mt][nt][qq] + bias[col]);
      }
}

// ---------------- K3: LSTM recurrence, v14 = R5 skeleton + role-clean lanes + 1 barrier.
// Proven base (R5, 1593us): 256 WGs x 512 thr, bid=q*32+b; WG q owns dims [q*32,+32)
// x 4 gates = 128 rows, k-split over 4 wave-pairs (kq=v>>1); per-thread w[32] (L2-
// resident by RA choice -- fastest weight supply of R5-R7); tagged {f16x2,step} u64
// agent-relaxed fabric (beat sc0-poll [R8 hang], CAS-poll [R9 storm], swap [R13]).
//
// R14 changes (no new structure, same fabric):
//  (a) polling moved to lanes 32..63 (word kq*32+l-32; readlane sources 32+i):
//      finale/publish/out (t<32) and x-prefetch lanes NEVER poll, polling lanes
//      NEVER store -> no poll loop waits on unrelated store acks (per-wave vmcnt,
//      R11 lesson) and barrier-entry drains have a full step of slack.
//  (b) single barrier per step: finale reads 16 partials from parity-double-
//      buffered pl[2][4][128] (both sides conflict-free); removes barrier[2] + rt.
//  (c) gate-packed proj: finale's x = one ushort4 load, prefetched one step ahead.
__device__ __forceinline__ float dot2(uint wp, uint hp, float acc) {
#if __has_builtin(__builtin_amdgcn_fdot2)
  return __builtin_amdgcn_fdot2(__builtin_bit_cast(f16x2, wp),
                                __builtin_bit_cast(f16x2, hp), acc, false);
#else
  f16x2 a = __builtin_bit_cast(f16x2, wp);
  f16x2 b = __builtin_bit_cast(f16x2, hp);
  return acc + (float)a.x * (float)b.x + (float)a.y * (float)b.y;
#endif
}

__device__ __forceinline__ float sigm(float v) { return 1.f / (1.f + __expf(-v)); }
__device__ __forceinline__ float tanh_(float v) { return 1.f - 2.f / (__expf(2.f * v) + 1.f); }
__device__ __forceinline__ float f16u(ushort u) { return (float)__builtin_bit_cast(f16, u); }

__global__ __launch_bounds__(512, 2)
void k_lstm(const int* __restrict__ evs,
            const f16* __restrict__ proj,
            const uint* __restrict__ whh_t,
            u64* hglob,                 // [32 batch][2 slot][128 pair] tagged words
            float* __restrict__ out) {
  int bid = blockIdx.x;
  int b = bid & 31, q = bid >> 5;      // 8 WGs of batch b share bid%8 -> same XCD
  int t = threadIdx.x;
  int v = t >> 6, l = t & 63;
  int kq = v >> 1;                     // k-quarter, wave-uniform
  int rid = (v & 1) * 64 + l;          // local gate-row 0..127
  int rowg = (rid >> 5) * 256 + q * 32 + (rid & 31);   // global gate-row

  __shared__ float pl[2][4][128];      // partials [parity][kq][rid]

  uint w[32];
#pragma unroll
  for (int i = 0; i < 32; ++i) w[i] = whh_t[(kq * 32 + i) * G4 + rowg];

  u64* hb = hglob + b * 256;           // [2][128]
  const int* ev = evs + b * SEQ;

  // t<32 carries x (4 gates, gate-packed) one step ahead; these lanes never poll.
  float x0 = 0.f, x1 = 0.f, x2 = 0.f, x3 = 0.f;
  if (t < 32) {
    ushort4 xv = *(const ushort4*)(proj + (long)ev[0] * G4 + (q * 32 + t) * 4);
    x0 = f16u(xv.x); x1 = f16u(xv.y); x2 = f16u(xv.z); x3 = f16u(xv.w);
  }

  float c = 0.f;

  for (int step = 0; step < SEQ; ++step) {
    // (1) poll h_{step-1}: lanes 32..63 of every wave (clean vmcnt: no stores here)
    int h0 = 0;
    if (step > 0 && l >= 32) {
      const u64* src = hb + ((step - 1) & 1) * 128 + kq * 32 + (l - 32);
      u64 val;
      do {
        val = __hip_atomic_load(src, __ATOMIC_RELAXED, __HIP_MEMORY_SCOPE_AGENT);
      } while ((uint)(val >> 32) != (uint)step);
      h0 = (int)(uint)val;
    }

    // (2) matvec partial over pairs [kq*32,+32): readlane sources are lanes 32..63
    float a0 = 0.f, a1 = 0.f, a2 = 0.f, a3 = 0.f;
#pragma unroll
    for (int i = 0; i < 32; i += 4) {
      a0 = dot2(w[i + 0], (uint)__builtin_amdgcn_readlane(h0, 32 + i + 0), a0);
      a1 = dot2(w[i + 1], (uint)__builtin_amdgcn_readlane(h0, 32 + i + 1), a1);
      a2 = dot2(w[i + 2], (uint)__builtin_amdgcn_readlane(h0, 32 + i + 2), a2);
      a3 = dot2(w[i + 3], (uint)__builtin_amdgcn_readlane(h0, 32 + i + 3), a3);
    }
    pl[step & 1][kq][rid] = (a0 + a1) + (a2 + a3);   // lanes stride-1: conflict-free

    __syncthreads();                   // the only barrier per step

    // (3) finale on t<32: 16 pl reads + x + activations + publish + out + x-prefetch
    if (t < 32) {
      const float (*pp)[128] = pl[step & 1];
      float s0 = (pp[0][t]      + pp[1][t])      + (pp[2][t]      + pp[3][t])      + x0;
      float s1 = (pp[0][32 + t] + pp[1][32 + t]) + (pp[2][32 + t] + pp[3][32 + t]) + x1;
      float s2 = (pp[0][64 + t] + pp[1][64 + t]) + (pp[2][64 + t] + pp[3][64 + t]) + x2;
      float s3 = (pp[0][96 + t] + pp[1][96 + t]) + (pp[2][96 + t] + pp[3][96 + t]) + x3;
      float iv = sigm(s0), fv = sigm(s1), gv = tanh_(s2), ov = sigm(s3);
      c = fv * c + iv * gv;
      float hval = ov * tanh_(c);
      float hA = __shfl(hval, 2 * (t & 15));
      float hB = __shfl(hval, 2 * (t & 15) + 1);
      if (t < 16) {                    // publish FIRST (critical path)
        f16x2 pk; pk.x = (f16)hA; pk.y = (f16)hB;
        uint pku = __builtin_bit_cast(uint, pk);
        u64 val = (u64)pku | ((u64)(uint)(step + 1) << 32);
        __hip_atomic_store(hb + (step & 1) * 128 + q * 16 + t, val,
                           __ATOMIC_RELAXED, __HIP_MEMORY_SCOPE_AGENT);
      }
      out[(step * BATCH + b) * HID + q * 32 + t] = hval;   // off the sync path
      if (step + 1 < SEQ) {            // x-prefetch, full step of slack
        ushort4 xv = *(const ushort4*)(proj + (long)ev[step + 1] * G4 + (q * 32 + t) * 4);
        x0 = f16u(xv.x); x1 = f16u(xv.y); x2 = f16u(xv.z); x3 = f16u(xv.w);
      }
    }
    // hazards: reads of pl[s&1] (finale s) complete before that thread reaches
    // barrier(s+1); next write of pl[s&1] is in step s+2, after barrier(s+1). Safe.
    // hb slot s&1 rewritten at end of step s+2 only after all WGs completed step
    // s+1's polls of that slot (publish order enforces it) -- R5-proven argument.
  }
}

extern "C" void kernel_launch(void* const* d_in, const int* in_sizes, int n_in,
                              void* d_out, int out_size, void* d_ws, size_t ws_size,
                              hipStream_t stream) {
  (void)n_in; (void)out_size; (void)ws_size;
  const int* evs = (const int*)d_in[0];
  const int* anc = (const int*)d_in[1];
  const float* weight = (const float*)d_in[2];
  const float* emb = (const float*)d_in[3];
  const float* wih = (const float*)d_in[4];
  const float* whh = (const float*)d_in[5];
  const float* bih = (const float*)d_in[6];
  const float* bhh = (const float*)d_in[7];
  int D = in_sizes[1] / N_TYPES;

  char* ws = (char*)d_ws;
  f16* path = (f16*)(ws);                       // 10000*256*2 = 5,120,000 (dead after k_gemm)
  f16* wih_h = (f16*)(ws + 5242880);            // 524,288
  uint* whh_t = (uint*)(ws + 5767168);          // 524,288
  float* bias = (float*)(ws + 6291456);         // 4,096
  f16* proj = (f16*)(ws + 6295552);             // 10000*1024*2 = 20,480,000 (gate-packed)
  u64* hglob = (u64*)(ws + 26775552);           // 32*2*128*8 = 65,536
  float* out = (float*)d_out;

  k_conv<<<1024, 256, 0, stream>>>(wih, whh, bih, bhh, wih_h, whh_t, bias);
  k_path<<<N_TYPES, 256, 0, stream>>>(anc, weight, emb, D, path);
  k_gemm<<<dim3(79, 8), 256, 0, stream>>>(path, wih_h, bias, proj);
  hipMemsetAsync(hglob, 0, 32 * 2 * 128 * 8, stream);   // zero tags (replay-safe)
  k_lstm<<<256, 512, 0, stream>>>(evs, proj, whh_t, hglob, out);
}